// Round 1
// baseline (1098.264 us; speedup 1.0000x reference)
//
#include <hip/hip_runtime.h>
#include <math.h>

typedef unsigned short u16;
typedef float floatx4 __attribute__((ext_vector_type(4)));
typedef __bf16 bf16x8 __attribute__((ext_vector_type(8)));

// Problem constants
#define BB   16
#define TQ   2048   // query length after convs (= 2H)
#define TK   1024   // key rows (= H)
#define HH   1024   // H
#define H2   2048   // 2H
#define QD   80
#define KD   256
#define NQ   2044
#define NKEY 1024

__device__ __forceinline__ u16 f2bf(float f) {
  unsigned int u = __float_as_uint(f);
  u = u + 0x7fffu + ((u >> 16) & 1u);
  return (u16)(u >> 16);
}
__device__ __forceinline__ float bf2f(u16 s) {
  return __uint_as_float(((unsigned int)s) << 16);
}

// ---------------- packing kernels ----------------
__global__ __launch_bounds__(256) void cast_bf_k(const float* __restrict__ in, u16* __restrict__ out, long n) {
  long i = (long)blockIdx.x * 256 + threadIdx.x;
  if (i < n) out[i] = f2bf(in[i]);
}

// in: R x C fp32, out: C x R bf16
__global__ __launch_bounds__(256) void transpose_bf_k(const float* __restrict__ in, u16* __restrict__ out, int R, int C) {
  long i = (long)blockIdx.x * 256 + threadIdx.x;
  if (i >= (long)R * C) return;
  int c = (int)(i / R), r = (int)(i % R);
  out[i] = f2bf(in[(long)r * C + c]);
}

// query (B,2044,80) -> qT (B,80,2048) bf16, zero-padded K tail
__global__ __launch_bounds__(256) void pack_qT_k(const float* __restrict__ query, u16* __restrict__ out) {
  long i = (long)blockIdx.x * 256 + threadIdx.x;
  if (i >= (long)BB * QD * 2048) return;
  int n = (int)(i & 2047);
  long rem = i >> 11;
  int c = (int)(rem % QD);
  int b = (int)(rem / QD);
  out[i] = (n < NQ) ? f2bf(query[((long)b * NQ + n) * QD + c]) : (u16)0;
}

// qlw2[h,n] = ql_w[h, n+2] for n<2044 else 0   (1024 x 2048)
__global__ __launch_bounds__(256) void pack_qlw2_k(const float* __restrict__ qlw, u16* __restrict__ out) {
  long i = (long)blockIdx.x * 256 + threadIdx.x;
  if (i >= (long)HH * 2048) return;
  int n = (int)(i & 2047);
  int h = (int)(i >> 11);
  out[i] = (n < NQ) ? f2bf(qlw[(long)h * H2 + n + 2]) : (u16)0;
}

// kc_w (1024,256,3) -> kcp (1024, 768) with kk = t*256+d
__global__ __launch_bounds__(256) void pack_kc_k(const float* __restrict__ kcw, u16* __restrict__ out) {
  long i = (long)blockIdx.x * 256 + threadIdx.x;
  if (i >= (long)HH * 768) return;
  int r = (int)(i % 768);
  int o = (int)(i / 768);
  int t = r >> 8, d = r & 255;
  out[i] = f2bf(kcw[((long)o * KD + d) * 3 + t]);
}

// key (B,1024,256) -> im2col (B, 1024, 768), kk = t*256+d, zero at boundaries
__global__ __launch_bounds__(256) void pack_im2col_k(const float* __restrict__ key, u16* __restrict__ out) {
  long i = (long)blockIdx.x * 256 + threadIdx.x;
  if (i >= (long)BB * NKEY * 768) return;
  int r = (int)(i % 768);
  long rem = i / 768;
  int n = (int)(rem % NKEY);
  int b = (int)(rem / NKEY);
  int t = r >> 8, d = r & 255;
  int src = n + t - 1;
  out[i] = (src >= 0 && src < NKEY) ? f2bf(key[((long)b * NKEY + src) * KD + d]) : (u16)0;
}

__global__ __launch_bounds__(256) void lgamma_tbl_k(float* __restrict__ tbl) {
  int i = blockIdx.x * 256 + threadIdx.x;
  if (i < 8192) tbl[i] = i ? (float)lgamma((double)i) : 0.0f;
}

// ---------------- small reductions ----------------
__global__ __launch_bounds__(256) void matvec_bias_k(const float* __restrict__ W, const float* __restrict__ x,
                                                     const float* __restrict__ b0, float* __restrict__ out, int K) {
  const int o = blockIdx.x;
  const float* row = W + (long)o * K;
  float s = 0.f;
  for (int k = threadIdx.x; k < K; k += 256) s += row[k] * x[k];
  __shared__ float red[256];
  red[threadIdx.x] = s; __syncthreads();
  for (int st = 128; st > 0; st >>= 1) { if (threadIdx.x < st) red[threadIdx.x] += red[threadIdx.x + st]; __syncthreads(); }
  if (!threadIdx.x) out[o] = red[0] + b0[o];
}

__global__ __launch_bounds__(256) void s1s0_k(const float* __restrict__ qlw, float* __restrict__ s1, float* __restrict__ s0) {
  const int h = blockIdx.x;
  const float* row = qlw + (long)h * H2;
  float s = 0.f;
  for (int m = 1 + threadIdx.x; m <= H2 - 2; m += 256) s += row[m];
  __shared__ float red[256];
  red[threadIdx.x] = s; __syncthreads();
  for (int st = 128; st > 0; st >>= 1) { if (threadIdx.x < st) red[threadIdx.x] += red[threadIdx.x + st]; __syncthreads(); }
  if (!threadIdx.x) { s1[h] = red[0]; s0[h] = row[0] + row[H2 - 1]; }
}

__global__ __launch_bounds__(256) void rownorm_k(const u16* __restrict__ X, float* __restrict__ out, int C) {
  const long r = blockIdx.x;
  const u16* row = X + r * C;
  float s = 0.f;
  for (int c = threadIdx.x; c < C; c += 256) { float f = bf2f(row[c]); s += f * f; }
  __shared__ float red[256];
  red[threadIdx.x] = s; __syncthreads();
  for (int st = 128; st > 0; st >>= 1) { if (threadIdx.x < st) red[threadIdx.x] += red[threadIdx.x + st]; __syncthreads(); }
  if (!threadIdx.x) out[r] = red[0];
}

// ---------------- MFMA GEMM: C[b] = A[b] @ B[b]^T (+ biases) ----------------
// A: M x K row-major bf16 (lda=K), B: N x K row-major bf16 (ldb=K), C: M x N (ldc=N)
// epilogue: + colb[n] + rowb[m] + r1m[m]*r1n[n] + r2m[m]*r2n[n]   (null = skip)
#define LDSP 40   // 32 + 8 pad (16B) -> 2-way LDS conflicts only (free per m136)

template<int OUT_BF>
__global__ __launch_bounds__(256) void gemm_bt(
    const u16* __restrict__ A, const u16* __restrict__ B, void* __restrict__ Cv,
    int M, int N, int K, long sA, long sB, long sC,
    const float* __restrict__ colb, const float* __restrict__ rowb,
    const float* __restrict__ r1m, const float* __restrict__ r1n,
    const float* __restrict__ r2m, const float* __restrict__ r2n)
{
  __shared__ __align__(16) u16 As[128 * LDSP];
  __shared__ __align__(16) u16 Bs[128 * LDSP];
  const int bz = blockIdx.z;
  const u16* Ab = A + (long)bz * sA;
  const u16* Bb = B + (long)bz * sB;
  const int tid  = threadIdx.x;
  const int lane = tid & 63;
  const int wm = ((tid >> 7) & 1) * 64;   // wave row offset
  const int wn = ((tid >> 6) & 1) * 64;   // wave col offset
  const int m0 = blockIdx.y * 128;
  const int n0 = blockIdx.x * 128;

  floatx4 acc[4][4];
#pragma unroll
  for (int a_ = 0; a_ < 4; a_++)
#pragma unroll
    for (int b_ = 0; b_ < 4; b_++) acc[a_][b_] = (floatx4){0.f, 0.f, 0.f, 0.f};

  const int lr = tid >> 2;          // 0..63 staging row
  const int lc = (tid & 3) << 3;    // 0,8,16,24 staging col
  const int fr = lane & 15;         // frag row/col within 16
  const int fk = (lane >> 4) << 3;  // frag k offset

  for (int kb = 0; kb < K; kb += 32) {
#pragma unroll
    for (int hh = 0; hh < 2; ++hh) {
      const int r = lr + hh * 64;
      { // A tile
        const int gr = m0 + r; const int gc = kb + lc;
        uint4 v;
        if (gr < M && gc + 8 <= K) {
          v = *reinterpret_cast<const uint4*>(Ab + (long)gr * K + gc);
        } else {
          union { u16 s[8]; uint4 v4; } u;
#pragma unroll
          for (int t = 0; t < 8; t++) u.s[t] = (gr < M && gc + t < K) ? Ab[(long)gr * K + gc + t] : (u16)0;
          v = u.v4;
        }
        *reinterpret_cast<uint4*>(&As[r * LDSP + lc]) = v;
      }
      { // B tile
        const int gr = n0 + r; const int gc = kb + lc;
        uint4 v;
        if (gr < N && gc + 8 <= K) {
          v = *reinterpret_cast<const uint4*>(Bb + (long)gr * K + gc);
        } else {
          union { u16 s[8]; uint4 v4; } u;
#pragma unroll
          for (int t = 0; t < 8; t++) u.s[t] = (gr < N && gc + t < K) ? Bb[(long)gr * K + gc + t] : (u16)0;
          v = u.v4;
        }
        *reinterpret_cast<uint4*>(&Bs[r * LDSP + lc]) = v;
      }
    }
    __syncthreads();
    bf16x8 af[4], bf[4];
#pragma unroll
    for (int mi = 0; mi < 4; mi++)
      af[mi] = *reinterpret_cast<const bf16x8*>(&As[(wm + mi * 16 + fr) * LDSP + fk]);
#pragma unroll
    for (int ni = 0; ni < 4; ni++)
      bf[ni] = *reinterpret_cast<const bf16x8*>(&Bs[(wn + ni * 16 + fr) * LDSP + fk]);
#pragma unroll
    for (int mi = 0; mi < 4; mi++)
#pragma unroll
      for (int ni = 0; ni < 4; ni++)
        acc[mi][ni] = __builtin_amdgcn_mfma_f32_16x16x32_bf16(af[mi], bf[ni], acc[mi][ni], 0, 0, 0);
    __syncthreads();
  }

  // epilogue: C/D layout col=lane&15, row=(lane>>4)*4+reg  [m89-verified]
  const int fr4 = (lane >> 4) << 2;
  const int fc  = lane & 15;
#pragma unroll
  for (int mi = 0; mi < 4; mi++) {
#pragma unroll
    for (int ni = 0; ni < 4; ni++) {
      const int gm0 = m0 + wm + mi * 16 + fr4;
      const int gn  = n0 + wn + ni * 16 + fc;
      if (gn < N) {
        const float cbv  = colb ? colb[gn] : 0.f;
        const float r1nv = r1n ? r1n[gn] : 0.f;
        const float r2nv = r2n ? r2n[gn] : 0.f;
#pragma unroll
        for (int rr = 0; rr < 4; rr++) {
          const int gm = gm0 + rr;
          if (gm < M) {
            float v = acc[mi][ni][rr] + cbv;
            if (rowb) v += rowb[gm];
            if (r1m)  v += r1m[gm] * r1nv;
            if (r2m)  v += r2m[gm] * r2nv;
            const long o = (long)bz * sC + (long)gm * N + gn;
            if (OUT_BF) ((u16*)Cv)[o] = f2bf(v);
            else        ((float*)Cv)[o] = v;
          }
        }
      }
    }
  }
}

// ---------------- fused dist + beta-binomial prior + log_softmax ----------------
__global__ __launch_bounds__(256) void finalize_k(
    const u16* __restrict__ S, const float* __restrict__ qn, const float* __restrict__ kn,
    const int* __restrict__ qlens, const int* __restrict__ klens,
    const float* __restrict__ tbl, float* __restrict__ out)
{
  const int i = blockIdx.x;            // 0..2047
  const int b = blockIdx.y;            // 0..15
  const int tid = threadIdx.x;
  const long rowoff = ((long)b * TQ + i) * TK;
  const int ql = qlens[b], kl = klens[b];
  const int n_ = (kl - 1 > 0) ? kl - 1 : 0;
  const int bb = (ql - i > 1) ? ql - i : 1;
  const float qni = qn[b * TQ + i];
#define TG(x) tbl[((x) < 8191) ? (x) : 8191]
  const float Crow = TG(n_ + 1) + TG(i + 1 + bb) - TG(i + 1) - TG(bb);
  const bool ivalid = (i < ql);

  float v[4];
  float lmax = -3.4e38f;
#pragma unroll
  for (int l = 0; l < 4; l++) {
    const int j = tid + (l << 8);
    const float Sv = bf2f(S[rowoff + j]);
    const float sq = fmaxf(qni + kn[b * TK + j] - 2.0f * Sv, 1e-12f);
    const float dist = -sqrtf(sq);
    float lp;
    if (ivalid && j < kl) {
      const int nmj = (n_ - j > 0) ? n_ - j : 0;
      lp = Crow - TG(j + 1) - TG(nmj + 1) + TG(i + j + 1) + TG(nmj + bb) - TG(i + j + 1 + nmj + bb);
    } else {
      lp = -1e9f;
    }
    v[l] = dist + lp;
    lmax = fmaxf(lmax, v[l]);
  }
  __shared__ float red[256];
  red[tid] = lmax; __syncthreads();
  for (int s = 128; s > 0; s >>= 1) { if (tid < s) red[tid] = fmaxf(red[tid], red[tid + s]); __syncthreads(); }
  const float gmax = red[0]; __syncthreads();
  float lsum = 0.f;
#pragma unroll
  for (int l = 0; l < 4; l++) lsum += expf(v[l] - gmax);
  red[tid] = lsum; __syncthreads();
  for (int s = 128; s > 0; s >>= 1) { if (tid < s) red[tid] += red[tid + s]; __syncthreads(); }
  const float lse = gmax + logf(red[0]);
#pragma unroll
  for (int l = 0; l < 4; l++) out[rowoff + tid + (l << 8)] = v[l] - lse;
#undef TG
}

// ---------------- host ----------------
extern "C" void kernel_launch(void* const* d_in, const int* in_sizes, int n_in,
                              void* d_out, int out_size, void* d_ws, size_t ws_size,
                              hipStream_t stream)
{
  (void)in_sizes; (void)n_in; (void)out_size;
  const float* query = (const float*)d_in[0];
  const float* key   = (const float*)d_in[1];
  const int*   qlens = (const int*)d_in[2];
  const int*   klens = (const int*)d_in[3];
  const float* qc1_w = (const float*)d_in[4];
  const float* qc1_b = (const float*)d_in[5];
  const float* qc2_w = (const float*)d_in[6];
  const float* qc2_b = (const float*)d_in[7];
  const float* ql_w  = (const float*)d_in[8];
  const float* ql_b  = (const float*)d_in[9];
  const float* kc_w  = (const float*)d_in[10];
  const float* kc_b  = (const float*)d_in[11];
  const float* kl1_w = (const float*)d_in[12];
  const float* kl1_b = (const float*)d_in[13];
  const float* kl2_w = (const float*)d_in[14];
  const float* kl2_b = (const float*)d_in[15];

  size_t off = 0;
  char* ws = (char*)d_ws;
  auto alloc = [&](size_t bytes) -> char* {
    char* p = ws + off; off += (bytes + 255) & ~(size_t)255; return p;
  };
  // Region A: dead before the cdist GEMM (S overlays it afterwards)
  u16* qc2w_bf = (u16*)alloc(2ull * H2 * H2);
  u16* qc1T_bf = (u16*)alloc(2ull * QD * H2);
  u16* kl2w_bf = (u16*)alloc(2ull * HH * H2);
  u16* kl1T_bf = (u16*)alloc(2ull * HH * H2);
  u16* qT_bf   = (u16*)alloc(2ull * BB * QD * 2048);
  u16* qlw2_bf = (u16*)alloc(2ull * HH * 2048);
  u16* kcp_bf  = (u16*)alloc(2ull * HH * 768);
  u16* kcol_bf = (u16*)alloc(2ull * BB * NKEY * 768);
  u16* Tp_bf   = (u16*)alloc(2ull * BB * HH * QD);
  u16* K1_bf   = (u16*)alloc(2ull * BB * HH * NKEY);
  u16* S_bf = (u16*)d_ws;                 // 67.1 MB, overlays region A (89.5 MB)
  // Region B: persistent
  float* tbl  = (float*)alloc(4ull * 8192);
  u16* Wq_bf  = (u16*)alloc(2ull * H2 * QD);
  u16* Wk_bf  = (u16*)alloc(2ull * HH * NKEY);
  float* bqm  = (float*)alloc(4ull * H2);
  float* bkv  = (float*)alloc(4ull * HH);
  float* s1v  = (float*)alloc(4ull * HH);
  float* s0v  = (float*)alloc(4ull * HH);
  u16* K3_bf  = (u16*)alloc(2ull * BB * TK * HH);
  float* qnv  = (float*)alloc(4ull * BB * TQ);
  float* knv  = (float*)alloc(4ull * BB * TK);
  u16* Q_bf   = (u16*)d_out;              // 67.1 MB parked in d_out (overwritten by finalize)

  auto blocks = [](long n) { return (unsigned)((n + 255) / 256); };

  // 1. lgamma table + packing
  lgamma_tbl_k<<<32, 256, 0, stream>>>(tbl);
  cast_bf_k<<<blocks((long)H2 * H2), 256, 0, stream>>>(qc2_w, qc2w_bf, (long)H2 * H2);
  transpose_bf_k<<<blocks((long)H2 * QD), 256, 0, stream>>>(qc1_w, qc1T_bf, H2, QD);
  cast_bf_k<<<blocks((long)HH * H2), 256, 0, stream>>>(kl2_w, kl2w_bf, (long)HH * H2);
  transpose_bf_k<<<blocks((long)H2 * HH), 256, 0, stream>>>(kl1_w, kl1T_bf, H2, HH);
  pack_qT_k<<<blocks((long)BB * QD * 2048), 256, 0, stream>>>(query, qT_bf);
  pack_qlw2_k<<<blocks((long)HH * 2048), 256, 0, stream>>>(ql_w, qlw2_bf);
  pack_kc_k<<<blocks((long)HH * 768), 256, 0, stream>>>(kc_w, kcp_bf);
  pack_im2col_k<<<blocks((long)BB * NKEY * 768), 256, 0, stream>>>(key, kcol_bf);

  // 2. bias folds (fp32)
  matvec_bias_k<<<H2, 256, 0, stream>>>(qc2_w, qc1_b, qc2_b, bqm, H2);
  matvec_bias_k<<<HH, 256, 0, stream>>>(kl2_w, kl1_b, kl2_b, bkv, H2);
  s1s0_k<<<HH, 256, 0, stream>>>(ql_w, s1v, s0v);

  // 3. weight folds: Wq = qc2_w @ qc1_w (2048x80), Wk = kl2_w @ kl1_w (1024x1024)
  gemm_bt<1><<<dim3(1, 16, 1), 256, 0, stream>>>(qc2w_bf, qc1T_bf, Wq_bf, H2, QD, H2,
      0, 0, 0, nullptr, nullptr, nullptr, nullptr, nullptr, nullptr);
  gemm_bt<1><<<dim3(8, 8, 1), 256, 0, stream>>>(kl2w_bf, kl1T_bf, Wk_bf, HH, NKEY, H2,
      0, 0, 0, nullptr, nullptr, nullptr, nullptr, nullptr, nullptr);

  // 4. query branch: Tp[b] (1024h x 80c) = qlw2 @ qT[b]^T ; Q[b] = Wq @ Tp[b]^T + biases
  gemm_bt<1><<<dim3(1, 8, BB), 256, 0, stream>>>(qlw2_bf, qT_bf, Tp_bf, HH, QD, 2048,
      0, (long)QD * 2048, (long)HH * QD, nullptr, nullptr, nullptr, nullptr, nullptr, nullptr);
  gemm_bt<1><<<dim3(8, 16, BB), 256, 0, stream>>>(Wq_bf, Tp_bf, Q_bf, H2, HH, QD,
      0, (long)HH * QD, (long)TQ * HH, ql_b, nullptr, bqm, s1v, qc2_b, s0v);

  // 5. key branch: K1[b] = kcp @ im2col[b]^T + kc_b[o] ; K3[b] = K1[b] @ Wk^T + bk[h]
  gemm_bt<1><<<dim3(8, 8, BB), 256, 0, stream>>>(kcp_bf, kcol_bf, K1_bf, HH, NKEY, 768,
      0, (long)NKEY * 768, (long)HH * NKEY, nullptr, kc_b, nullptr, nullptr, nullptr, nullptr);
  gemm_bt<1><<<dim3(8, 8, BB), 256, 0, stream>>>(K1_bf, Wk_bf, K3_bf, HH, NKEY, NKEY,
      (long)HH * NKEY, 0, (long)TK * HH, bkv, nullptr, nullptr, nullptr, nullptr, nullptr);

  // 6. row norms
  rownorm_k<<<BB * TQ, 256, 0, stream>>>(Q_bf, qnv, HH);
  rownorm_k<<<BB * TK, 256, 0, stream>>>(K3_bf, knv, HH);

  // 7. S[b] = Q[b] @ K3[b]^T  (bf16, overlays region A)
  gemm_bt<1><<<dim3(8, 16, BB), 256, 0, stream>>>(Q_bf, K3_bf, S_bf, TQ, TK, HH,
      (long)TQ * HH, (long)TK * HH, (long)TQ * TK, nullptr, nullptr, nullptr, nullptr, nullptr, nullptr);

  // 8. dist + prior + log_softmax -> d_out (fp32)
  finalize_k<<<dim3(TQ, BB, 1), 256, 0, stream>>>(S_bf, qnv, knv, qlens, klens, tbl, (float*)d_out);
}

// Round 2
// 852.054 us; speedup vs baseline: 1.2890x; 1.2890x over previous
//
#include <hip/hip_runtime.h>
#include <math.h>

typedef unsigned short u16;
typedef float floatx4 __attribute__((ext_vector_type(4)));
typedef __bf16 bf16x8 __attribute__((ext_vector_type(8)));

// Problem constants
#define BB   16
#define TQ   2048   // query length after convs (= 2H)
#define TK   1024   // key rows (= H)
#define HH   1024   // H
#define H2   2048   // 2H
#define QD   80
#define QDP  128    // QD padded to tile width (zero-filled)
#define KD   256
#define NQ   2044
#define NKEY 1024

__device__ __forceinline__ u16 f2bf(float f) {
  unsigned int u = __float_as_uint(f);
  u = u + 0x7fffu + ((u >> 16) & 1u);
  return (u16)(u >> 16);
}
__device__ __forceinline__ float bf2f(u16 s) {
  return __uint_as_float(((unsigned int)s) << 16);
}

// ---------------- packing kernels ----------------
__global__ __launch_bounds__(256) void cast_bf_k(const float* __restrict__ in, u16* __restrict__ out, long n) {
  long i = (long)blockIdx.x * 256 + threadIdx.x;
  if (i < n) out[i] = f2bf(in[i]);
}

// in: R x C fp32 -> out: Cp x R bf16, rows c >= C zero-filled
__global__ __launch_bounds__(256) void transpose_pad_bf_k(const float* __restrict__ in, u16* __restrict__ out,
                                                          int R, int C, int Cp) {
  long i = (long)blockIdx.x * 256 + threadIdx.x;
  if (i >= (long)Cp * R) return;
  int c = (int)(i / R), r = (int)(i % R);
  out[i] = (c < C) ? f2bf(in[(long)r * C + c]) : (u16)0;
}

// query (B,2044,80) -> qT (B,128,2048) bf16, zero-padded in both c and n
__global__ __launch_bounds__(256) void pack_qT_k(const float* __restrict__ query, u16* __restrict__ out) {
  long i = (long)blockIdx.x * 256 + threadIdx.x;
  if (i >= (long)BB * QDP * 2048) return;
  int n = (int)(i & 2047);
  long rem = i >> 11;
  int c = (int)(rem % QDP);
  int b = (int)(rem / QDP);
  out[i] = (c < QD && n < NQ) ? f2bf(query[((long)b * NQ + n) * QD + c]) : (u16)0;
}

// qlw2[h,n] = ql_w[h, n+2] for n<2044 else 0   (1024 x 2048)
__global__ __launch_bounds__(256) void pack_qlw2_k(const float* __restrict__ qlw, u16* __restrict__ out) {
  long i = (long)blockIdx.x * 256 + threadIdx.x;
  if (i >= (long)HH * 2048) return;
  int n = (int)(i & 2047);
  int h = (int)(i >> 11);
  out[i] = (n < NQ) ? f2bf(qlw[(long)h * H2 + n + 2]) : (u16)0;
}

// kc_w (1024,256,3) -> kcp (1024, 768) with kk = t*256+d
__global__ __launch_bounds__(256) void pack_kc_k(const float* __restrict__ kcw, u16* __restrict__ out) {
  long i = (long)blockIdx.x * 256 + threadIdx.x;
  if (i >= (long)HH * 768) return;
  int r = (int)(i % 768);
  int o = (int)(i / 768);
  int t = r >> 8, d = r & 255;
  out[i] = f2bf(kcw[((long)o * KD + d) * 3 + t]);
}

// key (B,1024,256) -> im2col (B, 1024, 768), kk = t*256+d, zero at boundaries
__global__ __launch_bounds__(256) void pack_im2col_k(const float* __restrict__ key, u16* __restrict__ out) {
  long i = (long)blockIdx.x * 256 + threadIdx.x;
  if (i >= (long)BB * NKEY * 768) return;
  int r = (int)(i % 768);
  long rem = i / 768;
  int n = (int)(rem % NKEY);
  int b = (int)(rem / NKEY);
  int t = r >> 8, d = r & 255;
  int src = n + t - 1;
  out[i] = (src >= 0 && src < NKEY) ? f2bf(key[((long)b * NKEY + src) * KD + d]) : (u16)0;
}

__global__ __launch_bounds__(256) void lgamma_tbl_k(float* __restrict__ tbl) {
  int i = blockIdx.x * 256 + threadIdx.x;
  if (i < 8192) tbl[i] = i ? (float)lgamma((double)i) : 0.0f;
}

// ---------------- small reductions ----------------
__global__ __launch_bounds__(256) void matvec_bias_k(const float* __restrict__ W, const float* __restrict__ x,
                                                     const float* __restrict__ b0, float* __restrict__ out, int K) {
  const int o = blockIdx.x;
  const float* row = W + (long)o * K;
  float s = 0.f;
  for (int k = threadIdx.x; k < K; k += 256) s += row[k] * x[k];
  __shared__ float red[256];
  red[threadIdx.x] = s; __syncthreads();
  for (int st = 128; st > 0; st >>= 1) { if (threadIdx.x < st) red[threadIdx.x] += red[threadIdx.x + st]; __syncthreads(); }
  if (!threadIdx.x) out[o] = red[0] + b0[o];
}

__global__ __launch_bounds__(256) void s1s0_k(const float* __restrict__ qlw, float* __restrict__ s1, float* __restrict__ s0) {
  const int h = blockIdx.x;
  const float* row = qlw + (long)h * H2;
  float s = 0.f;
  for (int m = 1 + threadIdx.x; m <= H2 - 2; m += 256) s += row[m];
  __shared__ float red[256];
  red[threadIdx.x] = s; __syncthreads();
  for (int st = 128; st > 0; st >>= 1) { if (threadIdx.x < st) red[threadIdx.x] += red[threadIdx.x + st]; __syncthreads(); }
  if (!threadIdx.x) { s1[h] = red[0]; s0[h] = row[0] + row[H2 - 1]; }
}

__global__ __launch_bounds__(256) void rownorm_k(const u16* __restrict__ X, float* __restrict__ out, int C) {
  const long r = blockIdx.x;
  const u16* row = X + r * C;
  float s = 0.f;
  for (int c = threadIdx.x; c < C; c += 256) { float f = bf2f(row[c]); s += f * f; }
  __shared__ float red[256];
  red[threadIdx.x] = s; __syncthreads();
  for (int st = 128; st > 0; st >>= 1) { if (threadIdx.x < st) red[threadIdx.x] += red[threadIdx.x + st]; __syncthreads(); }
  if (!threadIdx.x) out[r] = red[0];
}

// ---------------- MFMA GEMM (fast path): C[b] = A[b] @ B[b]^T (+ biases) ----------------
// Requires: M%128==0, N%128==0, K%32==0, all pointers 16B-aligned.
// A: M x K row-major bf16, B: N x K row-major bf16, C: M x N.
// m97 structure: global_load_lds width=16 staging, unpadded LDS (BKx2=64B rows).
// epilogue: + colb[n] + rowb[m] + r1m[m]*r1n[n] + r2m[m]*r2n[n]   (null = skip)

__device__ __forceinline__ void gld_lds16(const u16* g, u16* l) {
  __builtin_amdgcn_global_load_lds((const __attribute__((address_space(1))) void*)g,
                                   (__attribute__((address_space(3))) void*)l, 16, 0, 0);
}

__global__ __launch_bounds__(256) void gemm_bt(
    const u16* __restrict__ A, const u16* __restrict__ B, u16* __restrict__ C,
    int M, int N, int K, long sA, long sB, long sC,
    const float* __restrict__ colb, const float* __restrict__ rowb,
    const float* __restrict__ r1m, const float* __restrict__ r1n,
    const float* __restrict__ r2m, const float* __restrict__ r2n)
{
  __shared__ __align__(16) u16 As[128 * 32];   // 8 KB
  __shared__ __align__(16) u16 Bs[128 * 32];   // 8 KB
  const int bz = blockIdx.z;
  const int tid  = threadIdx.x;
  const int lane = tid & 63;
  const int wv = tid >> 6;                // wave 0..3
  const int wm = ((tid >> 7) & 1) * 64;   // wave row offset
  const int wn = ((tid >> 6) & 1) * 64;   // wave col offset
  const int m0 = blockIdx.y * 128;
  const int n0 = blockIdx.x * 128;

  // staging: wave wv covers rows [wv*32, wv*32+32) of both tiles, 2 instrs of 16 rows each
  const int srow = wv * 32 + (lane >> 2);       // lane's source row within tile (first instr)
  const int scol = (lane & 3) << 3;             // 0,8,16,24
  const u16* ga = A + (long)bz * sA + (long)(m0 + srow) * K + scol;
  const u16* gb = B + (long)bz * sB + (long)(n0 + srow) * K + scol;
  u16* la0 = &As[(wv * 32) * 32];
  u16* la1 = &As[(wv * 32 + 16) * 32];
  u16* lb0 = &Bs[(wv * 32) * 32];
  u16* lb1 = &Bs[(wv * 32 + 16) * 32];
  const long k16 = (long)16 * K;

  floatx4 acc[4][4];
#pragma unroll
  for (int a_ = 0; a_ < 4; a_++)
#pragma unroll
    for (int b_ = 0; b_ < 4; b_++) acc[a_][b_] = (floatx4){0.f, 0.f, 0.f, 0.f};

  const int fr = lane & 15;         // frag row/col within 16
  const int fk = (lane >> 4) << 3;  // frag k offset

  for (int kb = 0; kb < K; kb += 32) {
    gld_lds16(ga,       la0);
    gld_lds16(ga + k16, la1);
    gld_lds16(gb,       lb0);
    gld_lds16(gb + k16, lb1);
    ga += 32; gb += 32;
    __syncthreads();
    bf16x8 af[4], bfr[4];
#pragma unroll
    for (int mi = 0; mi < 4; mi++)
      af[mi] = *reinterpret_cast<const bf16x8*>(&As[(wm + mi * 16 + fr) * 32 + fk]);
#pragma unroll
    for (int ni = 0; ni < 4; ni++)
      bfr[ni] = *reinterpret_cast<const bf16x8*>(&Bs[(wn + ni * 16 + fr) * 32 + fk]);
#pragma unroll
    for (int mi = 0; mi < 4; mi++)
#pragma unroll
      for (int ni = 0; ni < 4; ni++)
        acc[mi][ni] = __builtin_amdgcn_mfma_f32_16x16x32_bf16(af[mi], bfr[ni], acc[mi][ni], 0, 0, 0);
    __syncthreads();
  }

  // epilogue: C/D layout col=lane&15, row=(lane>>4)*4+reg  [m89-verified]
  const int fr4 = (lane >> 4) << 2;
  const int fc  = lane & 15;
  u16* Cb = C + (long)bz * sC;
#pragma unroll
  for (int mi = 0; mi < 4; mi++) {
#pragma unroll
    for (int ni = 0; ni < 4; ni++) {
      const int gm0 = m0 + wm + mi * 16 + fr4;
      const int gn  = n0 + wn + ni * 16 + fc;
      const float cbv  = colb ? colb[gn] : 0.f;
      const float r1nv = r1n ? r1n[gn] : 0.f;
      const float r2nv = r2n ? r2n[gn] : 0.f;
#pragma unroll
      for (int rr = 0; rr < 4; rr++) {
        const int gm = gm0 + rr;
        float v = acc[mi][ni][rr] + cbv;
        if (rowb) v += rowb[gm];
        if (r1m)  v += r1m[gm] * r1nv;
        if (r2m)  v += r2m[gm] * r2nv;
        Cb[(long)gm * N + gn] = f2bf(v);
      }
    }
  }
}

// ---------------- fused dist + beta-binomial prior + log_softmax ----------------
__global__ __launch_bounds__(256) void finalize_k(
    const u16* __restrict__ S, const float* __restrict__ qn, const float* __restrict__ kn,
    const int* __restrict__ qlens, const int* __restrict__ klens,
    const float* __restrict__ tbl, float* __restrict__ out)
{
  const int i = blockIdx.x;            // 0..2047
  const int b = blockIdx.y;            // 0..15
  const int tid = threadIdx.x;
  const long rowoff = ((long)b * TQ + i) * TK;
  const int ql = qlens[b], kl = klens[b];
  const int n_ = (kl - 1 > 0) ? kl - 1 : 0;
  const int bb = (ql - i > 1) ? ql - i : 1;
  const float qni = qn[b * TQ + i];
#define TG(x) tbl[((x) < 8191) ? (x) : 8191]
  const float Crow = TG(n_ + 1) + TG(i + 1 + bb) - TG(i + 1) - TG(bb);
  const bool ivalid = (i < ql);

  float v[4];
  float lmax = -3.4e38f;
#pragma unroll
  for (int l = 0; l < 4; l++) {
    const int j = tid + (l << 8);
    const float Sv = bf2f(S[rowoff + j]);
    const float sq = fmaxf(qni + kn[b * TK + j] - 2.0f * Sv, 1e-12f);
    const float dist = -sqrtf(sq);
    float lp;
    if (ivalid && j < kl) {
      const int nmj = (n_ - j > 0) ? n_ - j : 0;
      lp = Crow - TG(j + 1) - TG(nmj + 1) + TG(i + j + 1) + TG(nmj + bb) - TG(i + j + 1 + nmj + bb);
    } else {
      lp = -1e9f;
    }
    v[l] = dist + lp;
    lmax = fmaxf(lmax, v[l]);
  }
  __shared__ float red[256];
  red[tid] = lmax; __syncthreads();
  for (int s = 128; s > 0; s >>= 1) { if (tid < s) red[tid] = fmaxf(red[tid], red[tid + s]); __syncthreads(); }
  const float gmax = red[0]; __syncthreads();
  float lsum = 0.f;
#pragma unroll
  for (int l = 0; l < 4; l++) lsum += expf(v[l] - gmax);
  red[tid] = lsum; __syncthreads();
  for (int s = 128; s > 0; s >>= 1) { if (tid < s) red[tid] += red[tid + s]; __syncthreads(); }
  const float lse = gmax + logf(red[0]);
#pragma unroll
  for (int l = 0; l < 4; l++) out[rowoff + tid + (l << 8)] = v[l] - lse;
#undef TG
}

// ---------------- host ----------------
extern "C" void kernel_launch(void* const* d_in, const int* in_sizes, int n_in,
                              void* d_out, int out_size, void* d_ws, size_t ws_size,
                              hipStream_t stream)
{
  (void)in_sizes; (void)n_in; (void)out_size; (void)ws_size;
  const float* query = (const float*)d_in[0];
  const float* key   = (const float*)d_in[1];
  const int*   qlens = (const int*)d_in[2];
  const int*   klens = (const int*)d_in[3];
  const float* qc1_w = (const float*)d_in[4];
  const float* qc1_b = (const float*)d_in[5];
  const float* qc2_w = (const float*)d_in[6];
  const float* qc2_b = (const float*)d_in[7];
  const float* ql_w  = (const float*)d_in[8];
  const float* ql_b  = (const float*)d_in[9];
  const float* kc_w  = (const float*)d_in[10];
  const float* kc_b  = (const float*)d_in[11];
  const float* kl1_w = (const float*)d_in[12];
  const float* kl1_b = (const float*)d_in[13];
  const float* kl2_w = (const float*)d_in[14];
  const float* kl2_b = (const float*)d_in[15];

  size_t off = 0;
  char* ws = (char*)d_ws;
  auto alloc = [&](size_t bytes) -> char* {
    char* p = ws + off; off += (bytes + 255) & ~(size_t)255; return p;
  };
  // Pool 0 (offset 0): fold weights + qT — all dead after the fold/Tp GEMMs.
  // kcol overlays it afterwards; S overlays everything in d_ws[0..67.1MB] at step 7.
  u16* qc2w_bf = (u16*)alloc(2ull * H2 * H2);        //  8.39 MB
  u16* qc1T_bf = (u16*)alloc(2ull * QDP * H2);       //  0.52 MB (padded 128x2048)
  u16* kl2w_bf = (u16*)alloc(2ull * HH * H2);        //  4.19 MB
  u16* kl1T_bf = (u16*)alloc(2ull * HH * H2);        //  4.19 MB
  u16* qT_bf   = (u16*)alloc(2ull * BB * QDP * 2048);//  8.39 MB (padded)  [pool0 = 25.69 MB]
  u16* kcol_bf = (u16*)d_ws;                         // 25.17 MB overlay of pool0
  u16* S_bf    = (u16*)d_ws;                         // 67.1 MB overlay of everything below region B
  u16* qlw2_bf = (u16*)alloc(2ull * HH * 2048);      //  4.19 MB
  u16* kcp_bf  = (u16*)alloc(2ull * HH * 768);       //  1.57 MB
  u16* Tp_bf   = (u16*)alloc(2ull * BB * HH * QDP);  //  4.19 MB (padded K)
  u16* K1_bf   = (u16*)alloc(2ull * BB * HH * NKEY); // 33.55 MB  [region A total ~69.2 MB >= 67.1]
  // Region B: persistent through finalize
  float* tbl  = (float*)alloc(4ull * 8192);
  u16* Wq_bf  = (u16*)alloc(2ull * H2 * QDP);        // 2048x128 (padded K)
  u16* Wk_bf  = (u16*)alloc(2ull * HH * NKEY);
  float* bqm  = (float*)alloc(4ull * H2);
  float* bkv  = (float*)alloc(4ull * HH);
  float* s1v  = (float*)alloc(4ull * HH);
  float* s0v  = (float*)alloc(4ull * HH);
  u16* K3_bf  = (u16*)alloc(2ull * BB * TK * HH);    // 33.55 MB
  float* qnv  = (float*)alloc(4ull * BB * TQ);
  float* knv  = (float*)alloc(4ull * BB * TK);
  u16* Q_bf   = (u16*)d_out;                         // 67.1 MB parked in d_out

  auto blocks = [](long n) { return (unsigned)((n + 255) / 256); };

  // 1. lgamma table + weight/query packing (key-branch kcol deferred: it overlays pool0)
  lgamma_tbl_k<<<32, 256, 0, stream>>>(tbl);
  cast_bf_k<<<blocks((long)H2 * H2), 256, 0, stream>>>(qc2_w, qc2w_bf, (long)H2 * H2);
  transpose_pad_bf_k<<<blocks((long)QDP * H2), 256, 0, stream>>>(qc1_w, qc1T_bf, H2, QD, QDP);
  cast_bf_k<<<blocks((long)HH * H2), 256, 0, stream>>>(kl2_w, kl2w_bf, (long)HH * H2);
  transpose_pad_bf_k<<<blocks((long)HH * H2), 256, 0, stream>>>(kl1_w, kl1T_bf, H2, HH, HH);
  pack_qT_k<<<blocks((long)BB * QDP * 2048), 256, 0, stream>>>(query, qT_bf);
  pack_qlw2_k<<<blocks((long)HH * 2048), 256, 0, stream>>>(ql_w, qlw2_bf);
  pack_kc_k<<<blocks((long)HH * 768), 256, 0, stream>>>(kc_w, kcp_bf);

  // 2. bias folds (fp32)
  matvec_bias_k<<<H2, 256, 0, stream>>>(qc2_w, qc1_b, qc2_b, bqm, H2);
  matvec_bias_k<<<HH, 256, 0, stream>>>(kl2_w, kl1_b, kl2_b, bkv, H2);
  s1s0_k<<<HH, 256, 0, stream>>>(ql_w, s1v, s0v);

  // 3. weight folds: Wq = qc2_w @ qc1_w (2048x128p), Wk = kl2_w @ kl1_w (1024x1024)
  gemm_bt<<<dim3(1, 16, 1), 256, 0, stream>>>(qc2w_bf, qc1T_bf, Wq_bf, H2, QDP, H2,
      0, 0, 0, nullptr, nullptr, nullptr, nullptr, nullptr, nullptr);
  gemm_bt<<<dim3(8, 8, 1), 256, 0, stream>>>(kl2w_bf, kl1T_bf, Wk_bf, HH, NKEY, H2,
      0, 0, 0, nullptr, nullptr, nullptr, nullptr, nullptr, nullptr);

  // 4. query branch: Tp[b] (1024 x 128p) = qlw2 @ qT[b]^T ; Q[b] = Wq @ Tp[b]^T + biases
  gemm_bt<<<dim3(1, 8, BB), 256, 0, stream>>>(qlw2_bf, qT_bf, Tp_bf, HH, QDP, 2048,
      0, (long)QDP * 2048, (long)HH * QDP, nullptr, nullptr, nullptr, nullptr, nullptr, nullptr);
  gemm_bt<<<dim3(8, 16, BB), 256, 0, stream>>>(Wq_bf, Tp_bf, Q_bf, H2, HH, QDP,
      0, (long)HH * QDP, (long)TQ * HH, ql_b, nullptr, bqm, s1v, qc2_b, s0v);

  // 5. key branch (kcol packed now — pool0 is dead): K1[b] = kcp @ im2col[b]^T + kc_b[o]
  pack_im2col_k<<<blocks((long)BB * NKEY * 768), 256, 0, stream>>>(key, kcol_bf);
  gemm_bt<<<dim3(8, 8, BB), 256, 0, stream>>>(kcp_bf, kcol_bf, K1_bf, HH, NKEY, 768,
      0, (long)NKEY * 768, (long)HH * NKEY, nullptr, kc_b, nullptr, nullptr, nullptr, nullptr);
  gemm_bt<<<dim3(8, 8, BB), 256, 0, stream>>>(K1_bf, Wk_bf, K3_bf, HH, NKEY, NKEY,
      (long)HH * NKEY, 0, (long)TK * HH, bkv, nullptr, nullptr, nullptr, nullptr, nullptr);

  // 6. row norms
  rownorm_k<<<BB * TQ, 256, 0, stream>>>(Q_bf, qnv, HH);
  rownorm_k<<<BB * TK, 256, 0, stream>>>(K3_bf, knv, HH);

  // 7. S[b] = Q[b] @ K3[b]^T  (bf16, overlays region A — K1/kcol/Tp all dead)
  gemm_bt<<<dim3(8, 16, BB), 256, 0, stream>>>(Q_bf, K3_bf, S_bf, TQ, TK, HH,
      (long)TQ * HH, (long)TK * HH, (long)TQ * TK, nullptr, nullptr, nullptr, nullptr, nullptr, nullptr);

  // 8. dist + prior + log_softmax -> d_out (fp32)
  finalize_k<<<dim3(TQ, BB, 1), 256, 0, stream>>>(S_bf, qnv, knv, qlens, klens, tbl, (float*)d_out);
}

// Round 4
// 711.601 us; speedup vs baseline: 1.5434x; 1.1974x over previous
//
#include <hip/hip_runtime.h>
#include <math.h>

typedef unsigned short u16;
typedef float floatx4 __attribute__((ext_vector_type(4)));
typedef __bf16 bf16x8 __attribute__((ext_vector_type(8)));

// Problem constants
#define BB   16
#define TQ   2048   // query length after convs (= 2H)
#define TK   1024   // key rows (= H)
#define HH   1024   // H
#define H2   2048   // 2H
#define QD   80
#define QDP  128    // QD padded to tile width (zero-filled)
#define KD   256
#define NQ   2044
#define NKEY 1024

__device__ __forceinline__ u16 f2bf(float f) {
  unsigned int u = __float_as_uint(f);
  u = u + 0x7fffu + ((u >> 16) & 1u);
  return (u16)(u >> 16);
}
__device__ __forceinline__ float bf2f(u16 s) {
  return __uint_as_float(((unsigned int)s) << 16);
}

// ---------------- fused prep: all weight/input packing + lgamma table ----------------
// segments (blocks): qc2w 16384 | qc1T 1024 | kl2w 8192 | kl1T 8192 | qT 16384 |
//                    qlw2 8192 | kcp 3072 | lgamma 32   => grid 61472
__global__ __launch_bounds__(256) void prep_all_k(
    const float* __restrict__ qc2_w, const float* __restrict__ qc1_w,
    const float* __restrict__ kl2_w, const float* __restrict__ kl1_w,
    const float* __restrict__ query, const float* __restrict__ ql_w,
    const float* __restrict__ kc_w,
    u16* __restrict__ qc2w, u16* __restrict__ qc1T, u16* __restrict__ kl2w,
    u16* __restrict__ kl1T, u16* __restrict__ qT, u16* __restrict__ qlw2,
    u16* __restrict__ kcp, float* __restrict__ tbl)
{
  long b = blockIdx.x;
  const int t = threadIdx.x;
  if (b < 16384) {                       // qc2w: cast (2048x2048)
    long i = b * 256 + t; qc2w[i] = f2bf(qc2_w[i]); return;
  }
  b -= 16384;
  if (b < 1024) {                        // qc1T: transpose+pad (2048x80)->(128x2048)
    long i = b * 256 + t;
    int c = (int)(i / H2), r = (int)(i % H2);
    qc1T[i] = (c < QD) ? f2bf(qc1_w[(long)r * QD + c]) : (u16)0; return;
  }
  b -= 1024;
  if (b < 8192) {                        // kl2w: cast (1024x2048)
    long i = b * 256 + t; kl2w[i] = f2bf(kl2_w[i]); return;
  }
  b -= 8192;
  if (b < 8192) {                        // kl1T: transpose (2048x1024)->(1024x2048)
    long i = b * 256 + t;
    int c = (int)(i / H2), r = (int)(i % H2);
    kl1T[i] = f2bf(kl1_w[(long)r * HH + c]); return;
  }
  b -= 8192;
  if (b < 16384) {                       // qT: (B,2044,80)->(B,128,2048), zero-pad c and n
    long i = b * 256 + t;
    int n = (int)(i & 2047);
    long rem = i >> 11;
    int c = (int)(rem % QDP);
    int bb = (int)(rem / QDP);
    qT[i] = (c < QD && n < NQ) ? f2bf(query[((long)bb * NQ + n) * QD + c]) : (u16)0; return;
  }
  b -= 16384;
  if (b < 8192) {                        // qlw2[h,n] = ql_w[h,n+2], n<2044 else 0
    long i = b * 256 + t;
    int n = (int)(i & 2047);
    int h = (int)(i >> 11);
    qlw2[i] = (n < NQ) ? f2bf(ql_w[(long)h * H2 + n + 2]) : (u16)0; return;
  }
  b -= 8192;
  if (b < 3072) {                        // kcp: (1024,256,3)->(1024,768), kk=t*256+d
    long i = b * 256 + t;
    int r = (int)(i % 768);
    int o = (int)(i / 768);
    int tt = r >> 8, d = r & 255;
    kcp[i] = f2bf(kc_w[((long)o * KD + d) * 3 + tt]); return;
  }
  b -= 3072;
  { int i = (int)(b * 256 + t); if (i < 8192) tbl[i] = i ? (float)lgamma((double)i) : 0.0f; }
}

// ---------------- fused bias folds ----------------
// grid = H2 (bqm) + HH (bkv) + HH (s1/s0) = 4096
__global__ __launch_bounds__(256) void fold_bias_k(
    const float* __restrict__ qc2_w, const float* __restrict__ qc1_b, const float* __restrict__ qc2_b,
    const float* __restrict__ kl2_w, const float* __restrict__ kl1_b, const float* __restrict__ kl2_b,
    const float* __restrict__ ql_w,
    float* __restrict__ bqm, float* __restrict__ bkv, float* __restrict__ s1v, float* __restrict__ s0v)
{
  const int bid = blockIdx.x, t = threadIdx.x;
  float s = 0.f;
  if (bid < H2) {
    const float* row = qc2_w + (long)bid * H2;
    for (int k = t; k < H2; k += 256) s += row[k] * qc1_b[k];
  } else if (bid < H2 + HH) {
    const float* row = kl2_w + (long)(bid - H2) * H2;
    for (int k = t; k < H2; k += 256) s += row[k] * kl1_b[k];
  } else {
    const float* row = ql_w + (long)(bid - H2 - HH) * H2;
    for (int m = 1 + t; m <= H2 - 2; m += 256) s += row[m];
  }
  __shared__ float red[256];
  red[t] = s; __syncthreads();
  for (int st = 128; st > 0; st >>= 1) { if (t < st) red[t] += red[t + st]; __syncthreads(); }
  if (!t) {
    if (bid < H2) bqm[bid] = red[0] + qc2_b[bid];
    else if (bid < H2 + HH) bkv[bid - H2] = red[0] + kl2_b[bid - H2];
    else {
      int h = bid - H2 - HH;
      s1v[h] = red[0];
      s0v[h] = ql_w[(long)h * H2] + ql_w[(long)h * H2 + H2 - 1];
    }
  }
}

// ---------------- fused row norms (Q then K3), C=1024 exact ----------------
__global__ __launch_bounds__(256) void rownorm2_k(const u16* __restrict__ Q, const u16* __restrict__ K3,
                                                  float* __restrict__ qn, float* __restrict__ kn) {
  const long r = blockIdx.x;
  const int t = threadIdx.x;
  const u16* row = (r < (long)BB * TQ) ? (Q + r * 1024) : (K3 + (r - (long)BB * TQ) * 1024);
  uint2 v = reinterpret_cast<const uint2*>(row)[t];
  float a0 = bf2f((u16)(v.x & 0xffff)), a1 = bf2f((u16)(v.x >> 16));
  float a2 = bf2f((u16)(v.y & 0xffff)), a3 = bf2f((u16)(v.y >> 16));
  float s = a0 * a0 + a1 * a1 + a2 * a2 + a3 * a3;
  __shared__ float red[256];
  red[t] = s; __syncthreads();
  for (int st = 128; st > 0; st >>= 1) { if (t < st) red[t] += red[t + st]; __syncthreads(); }
  if (!t) {
    if (r < (long)BB * TQ) qn[r] = red[0];
    else kn[r - (long)BB * TQ] = red[0];
  }
}

// ---------------- MFMA GEMM: C[b] = A[b] @ B[b]^T (+ biases) ----------------
// Requires: M%128==0, N%128==0, K%32==0, lda/ldb%8==0, 16B-aligned bases.
// A: M rows, lda stride; B: N rows, ldb stride; C: M x N (ldc=N).
// swap: blockIdx.x indexes m-tiles (XCD keyed on m -> per-XCD reuse of A panels).
// OUTF32 = 1: write fp32 (split-K partials); OUTF32 = 0: bf16 with epilogue
//   + colb[n] + rowb[m] + r1m[m]*r1n[n] + r2m[m]*r2n[n]  (null = skip)

__device__ __forceinline__ void gld_lds16(const u16* g, u16* l) {
  __builtin_amdgcn_global_load_lds((const __attribute__((address_space(1))) void*)g,
                                   (__attribute__((address_space(3))) void*)l, 16, 0, 0);
}

template<int OUTF32>
__global__ __launch_bounds__(256) void gemm_bt(
    const u16* __restrict__ A, const u16* __restrict__ B, void* __restrict__ Cv,
    int M, int N, int K, int lda, int ldb, int swap,
    long sA, long sB, long sC,
    const float* __restrict__ colb, const float* __restrict__ rowb,
    const float* __restrict__ r1m, const float* __restrict__ r1n,
    const float* __restrict__ r2m, const float* __restrict__ r2n)
{
  __shared__ __align__(16) u16 As[128 * 32];   // 8 KB
  __shared__ __align__(16) u16 Bs[128 * 32];   // 8 KB
  const int bz = blockIdx.z;
  const int tid  = threadIdx.x;
  const int lane = tid & 63;
  const int wv = tid >> 6;                // wave 0..3
  const int wm = ((tid >> 7) & 1) * 64;   // wave row offset
  const int wn = ((tid >> 6) & 1) * 64;   // wave col offset
  const int m0 = (swap ? blockIdx.x : blockIdx.y) * 128;
  const int n0 = (swap ? blockIdx.y : blockIdx.x) * 128;

  // staging: wave wv covers rows [wv*32, wv*32+32) of both tiles, 2 instrs of 16 rows each
  const int srow = wv * 32 + (lane >> 2);       // lane's source row within tile (first instr)
  const int scol = (lane & 3) << 3;             // 0,8,16,24
  const u16* ga = A + bz * sA + (long)(m0 + srow) * lda + scol;
  const u16* gb = B + bz * sB + (long)(n0 + srow) * ldb + scol;
  u16* la0 = &As[(wv * 32) * 32];
  u16* la1 = &As[(wv * 32 + 16) * 32];
  u16* lb0 = &Bs[(wv * 32) * 32];
  u16* lb1 = &Bs[(wv * 32 + 16) * 32];
  const long a16 = (long)16 * lda;
  const long b16 = (long)16 * ldb;

  floatx4 acc[4][4];
#pragma unroll
  for (int a_ = 0; a_ < 4; a_++)
#pragma unroll
    for (int b_ = 0; b_ < 4; b_++) acc[a_][b_] = (floatx4){0.f, 0.f, 0.f, 0.f};

  const int fr = lane & 15;         // frag row/col within 16
  const int fk = (lane >> 4) << 3;  // frag k offset

  for (int kb = 0; kb < K; kb += 32) {
    gld_lds16(ga,       la0);
    gld_lds16(ga + a16, la1);
    gld_lds16(gb,       lb0);
    gld_lds16(gb + b16, lb1);
    ga += 32; gb += 32;
    __syncthreads();
    bf16x8 af[4], bfr[4];
#pragma unroll
    for (int mi = 0; mi < 4; mi++)
      af[mi] = *reinterpret_cast<const bf16x8*>(&As[(wm + mi * 16 + fr) * 32 + fk]);
#pragma unroll
    for (int ni = 0; ni < 4; ni++)
      bfr[ni] = *reinterpret_cast<const bf16x8*>(&Bs[(wn + ni * 16 + fr) * 32 + fk]);
#pragma unroll
    for (int mi = 0; mi < 4; mi++)
#pragma unroll
      for (int ni = 0; ni < 4; ni++)
        acc[mi][ni] = __builtin_amdgcn_mfma_f32_16x16x32_bf16(af[mi], bfr[ni], acc[mi][ni], 0, 0, 0);
    __syncthreads();
  }

  // epilogue: C/D layout col=lane&15, row=(lane>>4)*4+reg  [m89-verified]
  const int fr4 = (lane >> 4) << 2;
  const int fc  = lane & 15;
  u16*   Cb16 = (u16*)Cv + (long)bz * sC;
  float* Cb32 = (float*)Cv + (long)bz * sC;
#pragma unroll
  for (int mi = 0; mi < 4; mi++) {
#pragma unroll
    for (int ni = 0; ni < 4; ni++) {
      const int gm0 = m0 + wm + mi * 16 + fr4;
      const int gn  = n0 + wn + ni * 16 + fc;
      const float cbv  = colb ? colb[gn] : 0.f;
      const float r1nv = r1n ? r1n[gn] : 0.f;
      const float r2nv = r2n ? r2n[gn] : 0.f;
#pragma unroll
      for (int rr = 0; rr < 4; rr++) {
        const int gm = gm0 + rr;
        float v = acc[mi][ni][rr] + cbv;
        if (rowb) v += rowb[gm];
        if (r1m)  v += r1m[gm] * r1nv;
        if (r2m)  v += r2m[gm] * r2nv;
        if (OUTF32) Cb32[(long)gm * N + gn] = v;
        else        Cb16[(long)gm * N + gn] = f2bf(v);
      }
    }
  }
}

// ---------------- split-K reduce: out_bf16 = sum_s P[s] ----------------
__global__ __launch_bounds__(256) void reduce_sk_k(const float* __restrict__ P, u16* __restrict__ out,
                                                   long MN, int S) {
  long i = ((long)blockIdx.x * 256 + threadIdx.x) * 4;
  if (i >= MN) return;
  float4 s = *reinterpret_cast<const float4*>(P + i);
  for (int t = 1; t < S; t++) {
    const float4 v = *reinterpret_cast<const float4*>(P + (long)t * MN + i);
    s.x += v.x; s.y += v.y; s.z += v.z; s.w += v.w;
  }
  union { u16 h[4]; uint2 u; } o;
  o.h[0] = f2bf(s.x); o.h[1] = f2bf(s.y); o.h[2] = f2bf(s.z); o.h[3] = f2bf(s.w);
  *reinterpret_cast<uint2*>(out + i) = o.u;
}

// key (B,1024,256) -> im2col (B, 1024, 768), kk = t*256+d, zero at boundaries
__global__ __launch_bounds__(256) void pack_im2col_k(const float* __restrict__ key, u16* __restrict__ out) {
  long i = (long)blockIdx.x * 256 + threadIdx.x;
  if (i >= (long)BB * NKEY * 768) return;
  int r = (int)(i % 768);
  long rem = i / 768;
  int n = (int)(rem % NKEY);
  int b = (int)(rem / NKEY);
  int t = r >> 8, d = r & 255;
  int src = n + t - 1;
  out[i] = (src >= 0 && src < NKEY) ? f2bf(key[((long)b * NKEY + src) * KD + d]) : (u16)0;
}

// ---------------- fused dist + beta-binomial prior + log_softmax ----------------
__global__ __launch_bounds__(256) void finalize_k(
    const u16* __restrict__ S, const float* __restrict__ qn, const float* __restrict__ kn,
    const int* __restrict__ qlens, const int* __restrict__ klens,
    const float* __restrict__ tbl, float* __restrict__ out)
{
  const int i = blockIdx.x;            // 0..2047
  const int b = blockIdx.y;            // 0..15
  const int tid = threadIdx.x;
  const long rowoff = ((long)b * TQ + i) * TK;
  const int ql = qlens[b], kl = klens[b];
  const int n_ = (kl - 1 > 0) ? kl - 1 : 0;
  const int bb = (ql - i > 1) ? ql - i : 1;
  const float qni = qn[b * TQ + i];
#define TG(x) tbl[((x) < 8191) ? (x) : 8191]
  const float Crow = TG(n_ + 1) + TG(i + 1 + bb) - TG(i + 1) - TG(bb);
  const bool ivalid = (i < ql);

  float v[4];
  float lmax = -3.4e38f;
#pragma unroll
  for (int l = 0; l < 4; l++) {
    const int j = tid + (l << 8);
    const float Sv = bf2f(S[rowoff + j]);
    const float sq = fmaxf(qni + kn[b * TK + j] - 2.0f * Sv, 1e-12f);
    const float dist = -sqrtf(sq);
    float lp;
    if (ivalid && j < kl) {
      const int nmj = (n_ - j > 0) ? n_ - j : 0;
      lp = Crow - TG(j + 1) - TG(nmj + 1) + TG(i + j + 1) + TG(nmj + bb) - TG(i + j + 1 + nmj + bb);
    } else {
      lp = -1e9f;
    }
    v[l] = dist + lp;
    lmax = fmaxf(lmax, v[l]);
  }
  __shared__ float red[256];
  red[tid] = lmax; __syncthreads();
  for (int s = 128; s > 0; s >>= 1) { if (tid < s) red[tid] = fmaxf(red[tid], red[tid + s]); __syncthreads(); }
  const float gmax = red[0]; __syncthreads();
  float lsum = 0.f;
#pragma unroll
  for (int l = 0; l < 4; l++) lsum += expf(v[l] - gmax);
  red[tid] = lsum; __syncthreads();
  for (int s = 128; s > 0; s >>= 1) { if (tid < s) red[tid] += red[tid + s]; __syncthreads(); }
  const float lse = gmax + logf(red[0]);
#pragma unroll
  for (int l = 0; l < 4; l++) out[rowoff + tid + (l << 8)] = v[l] - lse;
#undef TG
}

// ---------------- host ----------------
extern "C" void kernel_launch(void* const* d_in, const int* in_sizes, int n_in,
                              void* d_out, int out_size, void* d_ws, size_t ws_size,
                              hipStream_t stream)
{
  (void)in_sizes; (void)n_in; (void)out_size; (void)ws_size;
  const float* query = (const float*)d_in[0];
  const float* key   = (const float*)d_in[1];
  const int*   qlens = (const int*)d_in[2];
  const int*   klens = (const int*)d_in[3];
  const float* qc1_w = (const float*)d_in[4];
  const float* qc1_b = (const float*)d_in[5];
  const float* qc2_w = (const float*)d_in[6];
  const float* qc2_b = (const float*)d_in[7];
  const float* ql_w  = (const float*)d_in[8];
  const float* ql_b  = (const float*)d_in[9];
  const float* kc_w  = (const float*)d_in[10];
  const float* kc_b  = (const float*)d_in[11];
  const float* kl1_w = (const float*)d_in[12];
  const float* kl1_b = (const float*)d_in[13];
  const float* kl2_w = (const float*)d_in[14];
  const float* kl2_b = (const float*)d_in[15];

  size_t off = 0;
  char* ws = (char*)d_ws;
  auto alloc = [&](size_t bytes) -> char* {
    char* p = ws + off; off += (bytes + 255) & ~(size_t)255; return p;
  };
  // Pool 0: fold weights + qT — dead after the split-K fold GEMMs / Tp GEMM.
  // kcol overlays it afterwards; S overlays d_ws[0..67.1MB] at step 8.
  u16* qc2w_bf = (u16*)alloc(2ull * H2 * H2);        //  8.39 MB
  u16* qc1T_bf = (u16*)alloc(2ull * QDP * H2);       //  0.52 MB
  u16* kl2w_bf = (u16*)alloc(2ull * HH * H2);        //  4.19 MB
  u16* kl1T_bf = (u16*)alloc(2ull * HH * H2);        //  4.19 MB
  u16* qT_bf   = (u16*)alloc(2ull * BB * QDP * 2048);//  8.39 MB   [pool0 = 25.69 MB]
  u16* kcol_bf = (u16*)d_ws;                         // 25.17 MB overlay of pool0
  u16* S_bf    = (u16*)d_ws;                         // 67.1 MB overlay below region B
  u16* qlw2_bf = (u16*)alloc(2ull * HH * 2048);      //  4.19 MB
  u16* kcp_bf  = (u16*)alloc(2ull * HH * 768);       //  1.57 MB
  u16* Tp_bf   = (u16*)alloc(2ull * HH * 2048);      //  4.19 MB  Tp_all (1024 x 2048, col=b*128+c)
  u16* K1_bf   = (u16*)alloc(2ull * BB * HH * NKEY); // 33.55 MB; also the split-K partial pool
  float* Pbuf  = (float*)K1_bf;                      // fp32 partials (max 32 MB) — dead before K1 write
  // Region B: persistent through finalize (starts at ~69.2 MB > 67.1 MB S overlay)
  float* tbl  = (float*)alloc(4ull * 8192);
  u16* Wq_bf  = (u16*)alloc(2ull * H2 * QDP);
  u16* Wk_bf  = (u16*)alloc(2ull * HH * NKEY);
  float* bqm  = (float*)alloc(4ull * H2);
  float* bkv  = (float*)alloc(4ull * HH);
  float* s1v  = (float*)alloc(4ull * HH);
  float* s0v  = (float*)alloc(4ull * HH);
  u16* K3_bf  = (u16*)alloc(2ull * BB * TK * HH);    // 33.55 MB
  float* qnv  = (float*)alloc(4ull * BB * TQ);
  float* knv  = (float*)alloc(4ull * BB * TK);
  u16* Q_bf   = (u16*)d_out;                         // 67.1 MB parked in d_out

  // 1. fused prep (weights, qT, qlw2, kcp, lgamma) + bias folds
  prep_all_k<<<61472, 256, 0, stream>>>(qc2_w, qc1_w, kl2_w, kl1_w, query, ql_w, kc_w,
                                        qc2w_bf, qc1T_bf, kl2w_bf, kl1T_bf, qT_bf, qlw2_bf, kcp_bf, tbl);
  fold_bias_k<<<4096, 256, 0, stream>>>(qc2_w, qc1_b, qc2_b, kl2_w, kl1_b, kl2_b, ql_w,
                                        bqm, bkv, s1v, s0v);

  // 2. Wq = qc2_w @ qc1_w-fold (2048x128), split-K 16 (KS=128) -> fp32 partials
  gemm_bt<1><<<dim3(1, 16, 16), 256, 0, stream>>>(qc2w_bf, qc1T_bf, Pbuf, H2, QDP, 128,
      H2, H2, 0, 128, 128, (long)H2 * QDP,
      nullptr, nullptr, nullptr, nullptr, nullptr, nullptr);
  reduce_sk_k<<<256, 256, 0, stream>>>(Pbuf, Wq_bf, (long)H2 * QDP, 16);

  // 3. Wk = kl2_w @ kl1_w-fold (1024x1024), split-K 8 (KS=256) -> fp32 partials
  gemm_bt<1><<<dim3(8, 8, 8), 256, 0, stream>>>(kl2w_bf, kl1T_bf, Pbuf, HH, NKEY, 256,
      H2, H2, 0, 256, 256, (long)HH * NKEY,
      nullptr, nullptr, nullptr, nullptr, nullptr, nullptr);
  reduce_sk_k<<<1024, 256, 0, stream>>>(Pbuf, Wk_bf, (long)HH * NKEY, 8);

  // 4. Tp_all (1024 x 2048) = qlw2 @ qT_all^T, split-K 4 (KS=512) -> fp32 partials
  gemm_bt<1><<<dim3(16, 8, 4), 256, 0, stream>>>(qlw2_bf, qT_bf, Pbuf, HH, 2048, 512,
      2048, 2048, 0, 512, 512, (long)HH * 2048,
      nullptr, nullptr, nullptr, nullptr, nullptr, nullptr);
  reduce_sk_k<<<2048, 256, 0, stream>>>(Pbuf, Tp_bf, (long)HH * 2048, 4);

  // 5. Q[b] = Wq @ Tp[b]^T + biases  (B operand = Tp_all cols b*128.., ldb=2048) -> bf16
  gemm_bt<0><<<dim3(8, 16, BB), 256, 0, stream>>>(Wq_bf, Tp_bf, Q_bf, H2, HH, QDP,
      QDP, 2048, 0, 0, 128, (long)TQ * HH,
      ql_b, nullptr, bqm, s1v, qc2_b, s0v);

  // 6. key branch (kcol overlays pool0 — now dead) -> bf16
  pack_im2col_k<<<(unsigned)(((long)BB * NKEY * 768 + 255) / 256), 256, 0, stream>>>(key, kcol_bf);
  gemm_bt<0><<<dim3(8, 8, BB), 256, 0, stream>>>(kcp_bf, kcol_bf, K1_bf, HH, NKEY, 768,
      768, 768, 0, 0, (long)NKEY * 768, (long)HH * NKEY,
      nullptr, kc_b, nullptr, nullptr, nullptr, nullptr);
  gemm_bt<0><<<dim3(8, 8, BB), 256, 0, stream>>>(K1_bf, Wk_bf, K3_bf, HH, NKEY, NKEY,
      NKEY, NKEY, 1, (long)HH * NKEY, 0, (long)TK * HH,
      bkv, nullptr, nullptr, nullptr, nullptr, nullptr);

  // 7. row norms (Q then K3)
  rownorm2_k<<<BB * TQ + BB * TK, 256, 0, stream>>>(Q_bf, K3_bf, qnv, knv);

  // 8. S[b] = Q[b] @ K3[b]^T  (swap: XCD keyed on m -> Q panels fetched once per L2) -> bf16
  gemm_bt<0><<<dim3(16, 8, BB), 256, 0, stream>>>(Q_bf, K3_bf, S_bf, TQ, TK, HH,
      HH, HH, 1, (long)TQ * HH, (long)TK * HH, (long)TQ * TK,
      nullptr, nullptr, nullptr, nullptr, nullptr, nullptr);

  // 9. dist + prior + log_softmax -> d_out (fp32)
  finalize_k<<<dim3(TQ, BB, 1), 256, 0, stream>>>(S_bf, qnv, knv, qlens, klens, tbl, (float*)d_out);
}